// Round 6
// baseline (269.551 us; speedup 1.0000x reference)
//
#include <hip/hip_runtime.h>
#include <stdint.h>

// NVFP4Linear: M=128 (8x16), K=I=8192, N=O=8192
// d_in[0] hidden: f32 [128][8192]  (reference fp16 promoted to f32 by harness)
// d_in[1] weight: int32[8192][4096], one packed byte per int (low nibble = even k)
// d_in[2] weight_scale: f32 [8192][512] (per 16-k group)
// d_in[3] weight_scale_2: f32[1] ; d_in[4] input_scale: f32[1]
// d_out: f32 [128][8192]

typedef _Float16 half8 __attribute__((ext_vector_type(8)));
typedef float float4v __attribute__((ext_vector_type(4)));

__device__ __forceinline__ uint32_t perm_b32(uint32_t hi, uint32_t lo, uint32_t sel) {
  return __builtin_amdgcn_perm(hi, lo, sel);
}

// Async global->LDS DMA, 16B per lane. LDS dest must be the WAVE-UNIFORM base;
// HW adds lane*16. Global src is per-lane.
__device__ __forceinline__ void load_lds16(const uint4* g, uint4* l) {
  __builtin_amdgcn_global_load_lds((const __attribute__((address_space(1))) void*)g,
                                   (__attribute__((address_space(3))) void*)l,
                                   16, 0, 0);
}

// RNE round-trip through fp8 e4m3fn (x >= 0, finite)
__device__ __forceinline__ float e4m3_roundtrip(float x) {
  if (x < 0.015625f) {               // subnormal region: grid step 2^-9
    return __builtin_rintf(x * 512.0f) * 0.001953125f;
  }
  uint32_t u = __float_as_uint(x);
  u += 0x7FFFFu + ((u >> 20) & 1u);  // RNE to 3 mantissa bits
  u &= 0xFFF00000u;
  float y = __uint_as_float(u);
  return fminf(y, 448.0f);
}

// ---------------- Kernel 1: activation QDQ -> swizzled f16 A fragments ----------------
// A_sw fragment (kb, mb) = 64 lanes x 16B; lane l holds A[mb*16 + (l&15)][kb*32 + (l>>4)*8 + j]
__global__ __launch_bounds__(256)
void aqdq_kernel(const float* __restrict__ hs,
                 const float* __restrict__ isc,
                 uint2* __restrict__ asw) {
  const int t = blockIdx.x * 256 + threadIdx.x;   // 262144 total
  const int m = t >> 11;                          // row 0..127
  const int u = t & 2047;
  const int g = u >> 2;                           // group within row 0..511
  const int hq = u & 3;                           // quarter of group

  const float* p = hs + m * 8192 + g * 16 + hq * 4;
  float4 x = *(const float4*)p;

  float amax = fmaxf(fmaxf(fabsf(x.x), fabsf(x.y)), fmaxf(fabsf(x.z), fabsf(x.w)));
  amax = fmaxf(amax, __shfl_xor(amax, 1));
  amax = fmaxf(amax, __shfl_xor(amax, 2));

  float is = isc[0];
  float s = e4m3_roundtrip(amax / (6.0f * is));
  if (!(s > 0.0f)) s = 1.0f;
  float total = s * is;

  float xv[4] = {x.x, x.y, x.z, x.w};
  union { _Float16 h[4]; uint2 v; } qq;
#pragma unroll
  for (int i = 0; i < 4; ++i) {
    float r = xv[i] / total;         // correctly-rounded f32 div, matches jnp
    float a = fabsf(r);
    // E2M1 nearest; ties -> lower magnitude (searchsorted side='left')
    float v = (a <= 0.25f) ? 0.0f
            : (a <= 0.75f) ? 0.5f
            : (a <= 1.25f) ? 1.0f
            : (a <= 1.75f) ? 1.5f
            : (a <= 2.5f)  ? 2.0f
            : (a <= 3.5f)  ? 3.0f
            : (a <= 5.0f)  ? 4.0f : 6.0f;
    qq.h[i] = (_Float16)(copysignf(v, r) * total);  // exact in f16
  }

  const int k = g * 16 + hq * 4;
  const int kb = k >> 5;
  const int quad = (k >> 3) & 3;
  const int lane16 = (m & 15) | (quad << 4);
  const int mb = m >> 4;
  asw[((kb * 8 + mb) * 64 + lane16) * 2 + (hq & 1)] = qq.v;
}

// ---------------- fp4 decode: packed u32 (4 bytes = 8 codes) -> 8 scaled f16 ----------------
__device__ __forceinline__ half8 decode_u32(uint32_t b, float sf) {
  uint32_t ev = b & 0x0F0F0F0Fu;               // even-k nibbles
  uint32_t od = (b >> 4) & 0x0F0F0F0Fu;        // odd-k nibbles
  uint32_t evm = ev & 0x07070707u;
  uint32_t odm = od & 0x07070707u;
  uint32_t evs = (ev & 0x08080808u) << 4;      // sign -> byte-high bit (f16 bit15)
  uint32_t ods = (od & 0x08080808u) << 4;
  // f16 high bytes of {0,.5,1,1.5,2,3,4,6} = {00,38,3C,3E,40,42,44,46}
  uint32_t evh = perm_b32(0x46444240u, 0x3E3C3800u, evm) | evs;
  uint32_t odh = perm_b32(0x46444240u, 0x3E3C3800u, odm) | ods;
  union { uint32_t u[4]; half8 h; } r;
  r.u[0] = perm_b32(odh, evh, 0x04000000u) & 0xFF00FF00u; // (k1,k0)
  r.u[1] = perm_b32(odh, evh, 0x05000100u) & 0xFF00FF00u; // (k3,k2)
  r.u[2] = perm_b32(odh, evh, 0x06000200u) & 0xFF00FF00u; // (k5,k4)
  r.u[3] = perm_b32(odh, evh, 0x07000300u) & 0xFF00FF00u; // (k7,k6)
  _Float16 hsf = (_Float16)sf;
  half8 sv = {hsf, hsf, hsf, hsf, hsf, hsf, hsf, hsf};
  return r.h * sv;                              // v_pk_mul_f16 x4
}

// ---------------- Kernel 2: cooperative fused dequant GEMM, 64 KiB LDS / 2 blocks/CU -------
// Grid 512 = 64 n-blocks x 8 k-parts. Block: 8 waves; wave wv owns cols [nb*128+wv*16,+16).
// LDS = abuf 32 KiB (ring-4 A k-slices, DMA'd distance-2) + wtile 2 x 16 KiB (quarter-K
// packed-weight tiles) = 64 KiB -> 2 blocks/CU (16 waves/CU). __launch_bounds__(512,4).
// W path: per quarter (8 steps = 256 k), two sub-batches of 8 x int2 loads (512 B contiguous
// per col), issued 2 steps before extraction; extraction = 1 v_perm + 1 ds_write_b16 per col.
// FIFO-vmcnt ledger (stage = {A-DMA, S-load} pair, distance 2):
//   steady: vmcnt(4). W-issue steps: vmcnt(12) then vmcnt(20). Extraction steps: vmcnt(12)
//   then vmcnt(4). Tail: vmcnt(2), vmcnt(0). Derived op-by-op; see session notes.
// MODE 0: write f32 partials [kp][128][8192]; MODE 1: unsafeAtomicAdd fallback.
template<int MODE>
__global__ __launch_bounds__(512, 4)
void gemm_kernel(const uint4* __restrict__ asw,
                 const int* __restrict__ wq,
                 const float* __restrict__ wsc,
                 const float* __restrict__ ws2p,
                 float* __restrict__ dst) {
  __shared__ uint4 abuf[4][8][64];      // 32 KiB A ring (frag layout)
  __shared__ uint32_t wtile32[8192];    // 2 x 16 KiB packed-weight quarter-tiles (swizzled)
  uint16_t* wtile16 = (uint16_t*)wtile32;
  const int lane = threadIdx.x & 63;
  const int wv = threadIdx.x >> 6;      // wave 0..7 = col group
  const int quad = lane >> 4;
  const int kp = blockIdx.x & 7;        // k-part
  const int nb = blockIdx.x >> 3;       // n-tile 0..63
  const int col = nb * 128 + wv * 16 + (lane & 15);
  const float ws2 = ws2p[0];
  const float2* sp = (const float2*)(wsc + (size_t)col * 512 + kp * 64);
  const uint4* ap = asw + kp * 16384 + wv * 64 + lane;   // A frag (kb=kp*32+t, mb=wv)
  const int2* wp2 = (const int2*)wq;    // int2 = 8 B raw = 2 payload bytes = 4 k
  const int scol0 = nb * 128 + wv * 16;

  float4v acc[8];
#pragma unroll
  for (int mb = 0; mb < 8; ++mb) acc[mb] = (float4v){0.f, 0.f, 0.f, 0.f};

  float2 sreg[4];
  int2 wsta[8], wstb[8];

// 8 x 512B-contiguous loads: col scol0+HALF*8+j, quarter QQ, lane l -> k-off l*4 (4 codes)
#define W_ISSUE(DST, QQ, HALF)                                                    \
  {                                                                               \
    _Pragma("unroll")                                                             \
    for (int j = 0; j < 8; ++j)                                                   \
      DST[j] = wp2[(size_t)(scol0 + (HALF) * 8 + j) * 2048 + kp * 256 +           \
                   (QQ) * 64 + lane];                                             \
    __builtin_amdgcn_sched_barrier(0);                                            \
  }

// lane l: s=l>>3, q=(l>>1)&3, h=l&1; k-off = s*32+q*8+h*4 = l*4 (verified identity)
#define W_EXTRACT(SRC, QQ, HALF)                                                  \
  {                                                                               \
    __builtin_amdgcn_sched_barrier(0);                                            \
    const int s_loc = lane >> 3;                                                  \
    const int qd = (lane >> 1) & 3;                                               \
    const int hh = lane & 1;                                                      \
    _Pragma("unroll")                                                             \
    for (int j = 0; j < 8; ++j) {                                                 \
      uint32_t v = perm_b32((uint32_t)SRC[j].y, (uint32_t)SRC[j].x, 0x0C0C0400u); \
      const int cl = wv * 16 + (HALF) * 8 + j;                                    \
      wtile16[((((QQ) & 1) * 4096) + s_loc * 512 +                                \
               ((cl * 4 + qd) ^ (s_loc << 2))) * 2 + hh] = (uint16_t)v;           \
    }                                                                             \
    asm volatile("s_waitcnt lgkmcnt(0)" ::: "memory");                            \
    __builtin_amdgcn_sched_barrier(0);                                            \
  }

#define STEP(T, VN)                                                               \
  {                                                                               \
    if ((T) < 30) {                                                               \
      load_lds16(ap + ((T) + 2) * 512, &abuf[((T) + 2) & 3][wv][0]);              \
      sreg[((T) + 2) & 3] = sp[(T) + 2];                                          \
    }                                                                             \
    __builtin_amdgcn_sched_barrier(0);                                            \
    asm volatile("s_waitcnt vmcnt(" #VN ")" ::: "memory");                        \
    __builtin_amdgcn_s_barrier();                                                 \
    __builtin_amdgcn_sched_barrier(0);                                            \
    uint4 af[8];                                                                  \
    _Pragma("unroll")                                                             \
    for (int mb = 0; mb < 8; ++mb) af[mb] = abuf[(T) & 3][mb][lane];              \
    const int s_ = (T) & 7;                                                       \
    uint32_t wb_ = wtile32[(((T) >> 3) & 1) * 4096 + s_ * 512 +                   \
                           (((wv * 16 + (lane & 15)) * 4 + quad) ^ (s_ << 2))];   \
    float sA = ((quad & 2) ? sreg[(T) & 3].y : sreg[(T) & 3].x) * ws2;            \
    half8 bA = decode_u32(wb_, sA);                                               \
    _Pragma("unroll")                                                             \
    for (int mb = 0; mb < 8; ++mb) {                                              \
      union { uint4 u; half8 h; } a_;                                             \
      a_.u = af[mb];                                                              \
      acc[mb] = __builtin_amdgcn_mfma_f32_16x16x32_f16(a_.h, bA, acc[mb], 0, 0, 0);\
    }                                                                             \
  }

  // ---- prologue: W(q0) both halves, stage(0), stage(1); drain W(q0); extract; issue W(q1)
  W_ISSUE(wsta, 0, 0)
  W_ISSUE(wstb, 0, 1)
  load_lds16(ap, &abuf[0][wv][0]);
  sreg[0] = sp[0];
  load_lds16(ap + 512, &abuf[1][wv][0]);
  sreg[1] = sp[1];
  __builtin_amdgcn_sched_barrier(0);
  asm volatile("s_waitcnt vmcnt(4)" ::: "memory");   // W(q0) done; A0,S0,A1,S1 in flight
  W_EXTRACT(wsta, 0, 0)
  W_EXTRACT(wstb, 0, 1)
  W_ISSUE(wsta, 1, 0)
  W_ISSUE(wstb, 1, 1)

  // windows: q0 read T0-7 (buf0), q1 T8-15 (buf1), q2 T16-23 (buf0), q3 T24-31 (buf1)
  STEP(0, 20)
  STEP(1, 20)
  STEP(2, 4)                 // drains W(q1); extract into buf1 (buf1 unread until T8)
  W_EXTRACT(wsta, 1, 0)
  W_EXTRACT(wstb, 1, 1)
  STEP(3, 4)
  STEP(4, 4)
  STEP(5, 4)
  W_ISSUE(wsta, 2, 0)
  STEP(6, 12)
  W_ISSUE(wstb, 2, 1)
  STEP(7, 20)
  STEP(8, 12)                // retires W2a; buf0 free (q0 last read T7)
  W_EXTRACT(wsta, 2, 0)
  STEP(9, 4)                 // retires W2b
  W_EXTRACT(wstb, 2, 1)
  STEP(10, 4)
  STEP(11, 4)
  STEP(12, 4)
  STEP(13, 4)
  W_ISSUE(wsta, 3, 0)
  STEP(14, 12)
  W_ISSUE(wstb, 3, 1)
  STEP(15, 20)
  STEP(16, 12)               // retires W3a; buf1 free (q1 last read T15)
  W_EXTRACT(wsta, 3, 0)
  STEP(17, 4)                // retires W3b
  W_EXTRACT(wstb, 3, 1)
  STEP(18, 4)
  STEP(19, 4)
  STEP(20, 4)
  STEP(21, 4)
  STEP(22, 4)
  STEP(23, 4)
  STEP(24, 4)
  STEP(25, 4)
  STEP(26, 4)
  STEP(27, 4)
  STEP(28, 4)
  STEP(29, 4)
  STEP(30, 2)
  STEP(31, 0)
#undef STEP
#undef W_ISSUE
#undef W_EXTRACT

  // Epilogue. C/D layout: n = lane&15, m = quad*4 + reg (verified m89/m91)
  if (MODE == 0) {
    float* pp = dst + ((size_t)kp << 20) + col;
#pragma unroll
    for (int mb = 0; mb < 8; ++mb) {
      const int mrow = mb * 16 + quad * 4;
#pragma unroll
      for (int r = 0; r < 4; ++r) pp[(size_t)(mrow + r) * 8192] = acc[mb][r];
    }
  } else {
#pragma unroll
    for (int mb = 0; mb < 8; ++mb) {
      const int mrow = mb * 16 + quad * 4;
#pragma unroll
      for (int r = 0; r < 4; ++r)
        unsafeAtomicAdd(&dst[(size_t)(mrow + r) * 8192 + col], acc[mb][r]);
    }
  }
}

// ---------------- Kernel 3: k-part reduction (MODE-0 path) ----------------
__global__ __launch_bounds__(256)
void reduce_kernel(const float4* __restrict__ part, float4* __restrict__ out) {
  const int i = blockIdx.x * 256 + threadIdx.x;   // 262144 float4 = 1M floats
  float4 s = part[i];
#pragma unroll
  for (int p = 1; p < 8; ++p) {
    float4 b = part[(size_t)p * 262144 + i];
    s.x += b.x; s.y += b.y; s.z += b.z; s.w += b.w;
  }
  out[i] = s;
}

extern "C" void kernel_launch(void* const* d_in, const int* in_sizes, int n_in,
                              void* d_out, int out_size, void* d_ws, size_t ws_size,
                              hipStream_t stream) {
  (void)in_sizes; (void)n_in; (void)out_size;
  const float* hs  = (const float*)d_in[0];   // f32 [128][8192]
  const int* wq    = (const int*)d_in[1];     // int32 [8192][4096]
  const float* wsc = (const float*)d_in[2];   // f32 [8192][512]
  const float* ws2 = (const float*)d_in[3];   // f32 [1]
  const float* isc = (const float*)d_in[4];   // f32 [1]
  float* out       = (float*)d_out;           // f32 [128][8192]
  uint2* asw2      = (uint2*)d_ws;            // 2 MiB swizzled f16 A fragments (8B store view)
  const uint4* asw4 = (const uint4*)d_ws;     // same buffer, 16B fragment view

  aqdq_kernel<<<1024, 256, 0, stream>>>(hs, isc, asw2);

  const size_t need = ((size_t)2 << 20) + ((size_t)32 << 20);  // asw + partials
  if (ws_size >= need) {
    float* part = (float*)((char*)d_ws + ((size_t)2 << 20));   // f32 [8][128][8192]
    gemm_kernel<0><<<512, 512, 0, stream>>>(asw4, wq, wsc, ws2, part);
    reduce_kernel<<<1024, 256, 0, stream>>>((const float4*)part, (float4*)out);
  } else {
    hipMemsetAsync(out, 0, (size_t)128 * 8192 * 4, stream);
    gemm_kernel<1><<<512, 512, 0, stream>>>(asw4, wq, wsc, ws2, out);
  }
}

// Round 7
// 229.648 us; speedup vs baseline: 1.1738x; 1.1738x over previous
//
#include <hip/hip_runtime.h>
#include <stdint.h>

// NVFP4Linear: M=128 (8x16), K=I=8192, N=O=8192
// d_in[0] hidden: f32 [128][8192]  (reference fp16 promoted to f32 by harness)
// d_in[1] weight: int32[8192][4096], one packed byte per int (low nibble = even k)
// d_in[2] weight_scale: f32 [8192][512] (per 16-k group)
// d_in[3] weight_scale_2: f32[1] ; d_in[4] input_scale: f32[1]
// d_out: f32 [128][8192]

typedef _Float16 half8 __attribute__((ext_vector_type(8)));
typedef float float4v __attribute__((ext_vector_type(4)));

__device__ __forceinline__ uint32_t perm_b32(uint32_t hi, uint32_t lo, uint32_t sel) {
  return __builtin_amdgcn_perm(hi, lo, sel);
}

// Async global->LDS DMA, 16B per lane. LDS dest must be the WAVE-UNIFORM base;
// HW adds lane*16. Global src is per-lane.
__device__ __forceinline__ void load_lds16(const uint4* g, uint4* l) {
  __builtin_amdgcn_global_load_lds((const __attribute__((address_space(1))) void*)g,
                                   (__attribute__((address_space(3))) void*)l,
                                   16, 0, 0);
}

// RNE round-trip through fp8 e4m3fn (x >= 0, finite)
__device__ __forceinline__ float e4m3_roundtrip(float x) {
  if (x < 0.015625f) {               // subnormal region: grid step 2^-9
    return __builtin_rintf(x * 512.0f) * 0.001953125f;
  }
  uint32_t u = __float_as_uint(x);
  u += 0x7FFFFu + ((u >> 20) & 1u);  // RNE to 3 mantissa bits
  u &= 0xFFF00000u;
  float y = __uint_as_float(u);
  return fminf(y, 448.0f);
}

// ---------------- Kernel 1: activation QDQ -> swizzled f16 A fragments ----------------
// A_sw fragment (kb, mb) = 64 lanes x 16B; lane l holds A[mb*16 + (l&15)][kb*32 + (l>>4)*8 + j]
__global__ __launch_bounds__(256)
void aqdq_kernel(const float* __restrict__ hs,
                 const float* __restrict__ isc,
                 uint2* __restrict__ asw) {
  const int t = blockIdx.x * 256 + threadIdx.x;   // 262144 total
  const int m = t >> 11;                          // row 0..127
  const int u = t & 2047;
  const int g = u >> 2;                           // group within row 0..511
  const int hq = u & 3;                           // quarter of group

  const float* p = hs + m * 8192 + g * 16 + hq * 4;
  float4 x = *(const float4*)p;

  float amax = fmaxf(fmaxf(fabsf(x.x), fabsf(x.y)), fmaxf(fabsf(x.z), fabsf(x.w)));
  amax = fmaxf(amax, __shfl_xor(amax, 1));
  amax = fmaxf(amax, __shfl_xor(amax, 2));

  float is = isc[0];
  float s = e4m3_roundtrip(amax / (6.0f * is));
  if (!(s > 0.0f)) s = 1.0f;
  float total = s * is;

  float xv[4] = {x.x, x.y, x.z, x.w};
  union { _Float16 h[4]; uint2 v; } qq;
#pragma unroll
  for (int i = 0; i < 4; ++i) {
    float r = xv[i] / total;         // correctly-rounded f32 div, matches jnp
    float a = fabsf(r);
    // E2M1 nearest; ties -> lower magnitude (searchsorted side='left')
    float v = (a <= 0.25f) ? 0.0f
            : (a <= 0.75f) ? 0.5f
            : (a <= 1.25f) ? 1.0f
            : (a <= 1.75f) ? 1.5f
            : (a <= 2.5f)  ? 2.0f
            : (a <= 3.5f)  ? 3.0f
            : (a <= 5.0f)  ? 4.0f : 6.0f;
    qq.h[i] = (_Float16)(copysignf(v, r) * total);  // exact in f16
  }

  const int k = g * 16 + hq * 4;
  const int kb = k >> 5;
  const int quad = (k >> 3) & 3;
  const int lane16 = (m & 15) | (quad << 4);
  const int mb = m >> 4;
  asw[((kb * 8 + mb) * 64 + lane16) * 2 + (hq & 1)] = qq.v;
}

// ---------------- fp4 pair decode: 4 packed bytes (8 codes) -> 8 scaled f16 ----------------
__device__ __forceinline__ half8 decode_scale(int4 w, float sf) {
  uint32_t t0 = perm_b32((uint32_t)w.y, (uint32_t)w.x, 0x00000400u);
  uint32_t t1 = perm_b32((uint32_t)w.w, (uint32_t)w.z, 0x04000000u);
  uint32_t b  = perm_b32(t1, t0, 0x07060100u); // byte i = codes (k2i, k2i+1)
  uint32_t ev = b & 0x0F0F0F0Fu;               // even-k nibbles
  uint32_t od = (b >> 4) & 0x0F0F0F0Fu;        // odd-k nibbles
  uint32_t evm = ev & 0x07070707u;
  uint32_t odm = od & 0x07070707u;
  uint32_t evs = (ev & 0x08080808u) << 4;      // sign -> byte-high bit (f16 bit15)
  uint32_t ods = (od & 0x08080808u) << 4;
  // f16 high bytes of {0,.5,1,1.5,2,3,4,6} = {00,38,3C,3E,40,42,44,46}
  uint32_t evh = perm_b32(0x46444240u, 0x3E3C3800u, evm) | evs;
  uint32_t odh = perm_b32(0x46444240u, 0x3E3C3800u, odm) | ods;
  union { uint32_t u[4]; half8 h; } r;
  r.u[0] = perm_b32(odh, evh, 0x04000000u) & 0xFF00FF00u; // (k1,k0)
  r.u[1] = perm_b32(odh, evh, 0x05000100u) & 0xFF00FF00u; // (k3,k2)
  r.u[2] = perm_b32(odh, evh, 0x06000200u) & 0xFF00FF00u; // (k5,k4)
  r.u[3] = perm_b32(odh, evh, 0x07000300u) & 0xFF00FF00u; // (k7,k6)
  _Float16 hsf = (_Float16)sf;
  half8 sv = {hsf, hsf, hsf, hsf, hsf, hsf, hsf, hsf};
  return r.h * sv;                              // v_pk_mul_f16 x4
}

// ---------------- Kernel 2: cooperative fused dequant GEMM, windowed schedule -------------
// Grid 512 = 64 n-blocks x 8 k-parts. Block: 8 waves; wave wv owns cols [nb*128+wv*16,+16).
// WINDOW = 4 MFMA-steps (128 k). Per window w: issue ALL of window w+1's loads up front
// (4x A-DMA global_load_lds, 4x weight int4, 2x scale float4 = 10 VMEM ops), run 4 steps
// {8x ds_read_b128 + decode + 8 MFMA} from the CURRENT buffers, then ONE vmcnt(0) + ONE
// s_barrier per window (8 barriers total vs 32). Load slack = a full window >> gather tail
// latency; 2 blocks/CU (64 KiB LDS) provide async phase overlap.
// Safety: DMA(w+1) writes abuf[(w+1)&1]; steps read abuf[w&1] (disjoint). Barrier(w) follows
// every wave's vmcnt(0), certifying all of abuf[(w+1)&1] before any wave enters window w+1.
// MODE 0: write f32 partials [kp][128][8192]; MODE 1: unsafeAtomicAdd fallback.
template<int MODE>
__global__ __launch_bounds__(512, 4)
void gemm_kernel(const uint4* __restrict__ asw,
                 const int* __restrict__ wq,
                 const float* __restrict__ wsc,
                 const float* __restrict__ ws2p,
                 float* __restrict__ dst) {
  __shared__ uint4 abuf[2][4][8][64];   // 64 KiB: [buf][step][mb][lane], dbuf A windows
  const int lane = threadIdx.x & 63;
  const int wv = threadIdx.x >> 6;      // wave 0..7 = col group
  const int quad = lane >> 4;
  const int kp = blockIdx.x & 7;        // k-part
  const int nb = blockIdx.x >> 3;       // n-tile 0..63
  const int col = nb * 128 + wv * 16 + (lane & 15);
  const float ws2 = ws2p[0];
  // weight: int4 idx = col*1024 + kp*128 + t*4 + quad   (t = global 32k-step, 0..31)
  const int4* wp = (const int4*)wq + (size_t)col * 1024 + kp * 128 + quad;
  // scales: float4 idx = (col*512 + kp*64)/4 + w*2 + j  (8 scales per window per col)
  const float4v* sp4 = (const float4v*)(wsc + (size_t)col * 512 + kp * 64);
  // A frags: asw + kp*16384 + t*512 + wv*64 + lane (per-lane src for DMA)
  const uint4* ap = asw + kp * 16384 + wv * 64 + lane;

  float4v acc[8];
#pragma unroll
  for (int mb = 0; mb < 8; ++mb) acc[mb] = (float4v){0.f, 0.f, 0.f, 0.f};

  int4 wA[4], wB[4];
  float4v sA[2], sB[2];

  // ---- prologue: window 0 loads, then certify ----
#pragma unroll
  for (int s = 0; s < 4; ++s) load_lds16(ap + s * 512, &abuf[0][s][wv][0]);
#pragma unroll
  for (int s = 0; s < 4; ++s) wA[s] = wp[s * 4];
  sA[0] = sp4[0];
  sA[1] = sp4[1];
  __builtin_amdgcn_sched_barrier(0);
  asm volatile("s_waitcnt vmcnt(0)" ::: "memory");
  __builtin_amdgcn_s_barrier();
  __builtin_amdgcn_sched_barrier(0);

#define WINDOW(W, WCUR, SCUR, WNXT, SNXT)                                         \
  {                                                                               \
    if ((W) < 7) {                                                                \
      _Pragma("unroll")                                                           \
      for (int s = 0; s < 4; ++s)                                                 \
        load_lds16(ap + (((W) + 1) * 4 + s) * 512,                                \
                   &abuf[((W) + 1) & 1][s][wv][0]);                               \
      _Pragma("unroll")                                                           \
      for (int s = 0; s < 4; ++s) WNXT[s] = wp[(((W) + 1) * 4 + s) * 4];          \
      SNXT[0] = sp4[((W) + 1) * 2];                                               \
      SNXT[1] = sp4[((W) + 1) * 2 + 1];                                           \
    }                                                                             \
    __builtin_amdgcn_sched_barrier(0);                                            \
    _Pragma("unroll")                                                             \
    for (int s = 0; s < 4; ++s) {                                                 \
      uint4 af[8];                                                                \
      _Pragma("unroll")                                                           \
      for (int mb = 0; mb < 8; ++mb) af[mb] = abuf[(W) & 1][s][mb][lane];         \
      float sc = SCUR[s >> 1][(s & 1) * 2 + (quad >> 1)] * ws2;                   \
      half8 bA = decode_scale(WCUR[s], sc);                                       \
      _Pragma("unroll")                                                           \
      for (int mb = 0; mb < 8; ++mb) {                                            \
        union { uint4 u; half8 h; } a_;                                           \
        a_.u = af[mb];                                                            \
        acc[mb] = __builtin_amdgcn_mfma_f32_16x16x32_f16(a_.h, bA, acc[mb], 0, 0, 0); \
      }                                                                           \
    }                                                                             \
    __builtin_amdgcn_sched_barrier(0);                                            \
    asm volatile("s_waitcnt vmcnt(0)" ::: "memory");                              \
    __builtin_amdgcn_s_barrier();                                                 \
    __builtin_amdgcn_sched_barrier(0);                                            \
  }

  WINDOW(0, wA, sA, wB, sB)
  WINDOW(1, wB, sB, wA, sA)
  WINDOW(2, wA, sA, wB, sB)
  WINDOW(3, wB, sB, wA, sA)
  WINDOW(4, wA, sA, wB, sB)
  WINDOW(5, wB, sB, wA, sA)
  WINDOW(6, wA, sA, wB, sB)
  WINDOW(7, wB, sB, wA, sA)
#undef WINDOW

  // Epilogue. C/D layout: n = lane&15, m = quad*4 + reg (verified m89/m91)
  if (MODE == 0) {
    float* pp = dst + ((size_t)kp << 20) + col;
#pragma unroll
    for (int mb = 0; mb < 8; ++mb) {
      const int mrow = mb * 16 + quad * 4;
#pragma unroll
      for (int r = 0; r < 4; ++r) pp[(size_t)(mrow + r) * 8192] = acc[mb][r];
    }
  } else {
#pragma unroll
    for (int mb = 0; mb < 8; ++mb) {
      const int mrow = mb * 16 + quad * 4;
#pragma unroll
      for (int r = 0; r < 4; ++r)
        unsafeAtomicAdd(&dst[(size_t)(mrow + r) * 8192 + col], acc[mb][r]);
    }
  }
}

// ---------------- Kernel 3: k-part reduction (MODE-0 path) ----------------
__global__ __launch_bounds__(256)
void reduce_kernel(const float4* __restrict__ part, float4* __restrict__ out) {
  const int i = blockIdx.x * 256 + threadIdx.x;   // 262144 float4 = 1M floats
  float4 s = part[i];
#pragma unroll
  for (int p = 1; p < 8; ++p) {
    float4 b = part[(size_t)p * 262144 + i];
    s.x += b.x; s.y += b.y; s.z += b.z; s.w += b.w;
  }
  out[i] = s;
}

extern "C" void kernel_launch(void* const* d_in, const int* in_sizes, int n_in,
                              void* d_out, int out_size, void* d_ws, size_t ws_size,
                              hipStream_t stream) {
  (void)in_sizes; (void)n_in; (void)out_size;
  const float* hs  = (const float*)d_in[0];   // f32 [128][8192]
  const int* wq    = (const int*)d_in[1];     // int32 [8192][4096]
  const float* wsc = (const float*)d_in[2];   // f32 [8192][512]
  const float* ws2 = (const float*)d_in[3];   // f32 [1]
  const float* isc = (const float*)d_in[4];   // f32 [1]
  float* out       = (float*)d_out;           // f32 [128][8192]
  uint2* asw2      = (uint2*)d_ws;            // 2 MiB swizzled f16 A fragments (8B store view)
  const uint4* asw4 = (const uint4*)d_ws;     // same buffer, 16B fragment view

  aqdq_kernel<<<1024, 256, 0, stream>>>(hs, isc, asw2);

  const size_t need = ((size_t)2 << 20) + ((size_t)32 << 20);  // asw + partials
  if (ws_size >= need) {
    float* part = (float*)((char*)d_ws + ((size_t)2 << 20));   // f32 [8][128][8192]
    gemm_kernel<0><<<512, 512, 0, stream>>>(asw4, wq, wsc, ws2, part);
    reduce_kernel<<<1024, 256, 0, stream>>>((const float4*)part, (float4*)out);
  } else {
    hipMemsetAsync(out, 0, (size_t)128 * 8192 * 4, stream);
    gemm_kernel<1><<<512, 512, 0, stream>>>(asw4, wq, wsc, ws2, out);
  }
}